// Round 3
// baseline (460.846 us; speedup 1.0000x reference)
//
#include <hip/hip_runtime.h>

#define NB 128
#define LL 512
#define DD 768
#define JJ 32
#define SS 33
#define DM 200

typedef __attribute__((ext_vector_type(8))) short bf8_t;   // 8 bf16 (4 VGPRs)
typedef __attribute__((ext_vector_type(4))) float f4_t;    // MFMA C/D

static __device__ __forceinline__ unsigned short f2bf(float f) {
  unsigned u = __float_as_uint(f);
  return (unsigned short)((u + 0x7FFFu + ((u >> 16) & 1u)) >> 16);  // RNE
}

// One 16x16 MFMA tile, K = 32*KS, A/W row-major with stride lda/ldw elements,
// pointers pre-offset to (row, koff). Works for global or LDS pointers.
template<int KS>
static __device__ __forceinline__ f4_t mfma_tile(
    const unsigned short* pa, const unsigned short* pw)
{
  f4_t acc = {0.f, 0.f, 0.f, 0.f};
  bf8_t a = *(const bf8_t*)pa;
  bf8_t w = *(const bf8_t*)pw;
#pragma unroll
  for (int s = 1; s < KS; ++s) {
    bf8_t a2 = *(const bf8_t*)(pa + 32 * s);
    bf8_t w2 = *(const bf8_t*)(pw + 32 * s);
    acc = __builtin_amdgcn_mfma_f32_16x16x32_bf16(a, w, acc, 0, 0, 0);
    a = a2; w = w2;
  }
  acc = __builtin_amdgcn_mfma_f32_16x16x32_bf16(a, w, acc, 0, 0, 0);
  return acc;
}

// ---------------------------------------------------------------------------
// Fused per-segment score + softmax + weighted pooling -> bf16 pooled.
// ---------------------------------------------------------------------------
__global__ __launch_bounds__(256) void pool_kernel(
    const float* __restrict__ hidden, const int* __restrict__ clause,
    const float* __restrict__ fc5w, unsigned short* __restrict__ pooled_bf)
{
  int blk = blockIdx.x;          // b*33 + s
  int b = blk / SS;
  int s = blk - b * SS;
  int t0 = (s == 0) ? 0 : clause[b * JJ + s - 1];
  int t1 = (s == JJ) ? LL : clause[b * JJ + s];
  int nt = t1 - t0;
  if (nt > 64) nt = 64;
  if (nt < 1) nt = 1;

  __shared__ float wsm[64];
  int tid = threadIdx.x;
  int wave = tid >> 6, lane = tid & 63;

  const float4* w4 = (const float4*)fc5w;
  for (int t = t0 + wave; t < t0 + nt; t += 4) {
    const float4* hp = (const float4*)(hidden + ((long long)b * LL + t) * DD);
    float acc = 0.f;
#pragma unroll
    for (int i = 0; i < 3; ++i) {
      float4 h = hp[lane + 64 * i];
      float4 w = w4[lane + 64 * i];
      acc += h.x * w.x + h.y * w.y + h.z * w.z + h.w * w.w;
    }
#pragma unroll
    for (int off = 32; off; off >>= 1) acc += __shfl_xor(acc, off);
    if (lane == 0) wsm[t - t0] = acc;
  }
  __syncthreads();

  if (wave == 0) {
    float v = (lane < nt) ? wsm[lane] : -__builtin_inff();
    float mx = v;
#pragma unroll
    for (int off = 32; off; off >>= 1) mx = fmaxf(mx, __shfl_xor(mx, off));
    float e = (lane < nt) ? __expf(v - mx) : 0.f;
    float sm = e;
#pragma unroll
    for (int off = 32; off; off >>= 1) sm += __shfl_xor(sm, off);
    if (lane < nt) wsm[lane] = e / sm;
  }
  __syncthreads();

  if (tid < 192) {
    const float4* base = (const float4*)(hidden + ((long long)b * LL + t0) * DD);
    float4 acc = make_float4(0.f, 0.f, 0.f, 0.f);
#pragma unroll 4
    for (int t = 0; t < nt; ++t) {
      float w = wsm[t];
      float4 h = base[t * 192 + tid];
      acc.x = fmaf(w, h.x, acc.x); acc.y = fmaf(w, h.y, acc.y);
      acc.z = fmaf(w, h.z, acc.z); acc.w = fmaf(w, h.w, acc.w);
    }
    ushort4 o;
    o.x = f2bf(acc.x); o.y = f2bf(acc.y); o.z = f2bf(acc.z); o.w = f2bf(acc.w);
    *(ushort4*)(pooled_bf + (long long)blk * DD + tid * 4) = o;
  }
}

// ---------------------------------------------------------------------------
// Convert + pad all weights fp32 -> bf16.
// fc1: [208][768]  ain: [608][224]  aout/lin1/lin2: [208][224]
// ---------------------------------------------------------------------------
__global__ __launch_bounds__(256) void convert_w(
    const float* __restrict__ fc1_w, const float* __restrict__ ain_w,
    const float* __restrict__ aout_w, const float* __restrict__ lin1_w,
    const float* __restrict__ lin2_w,
    unsigned short* __restrict__ fc1_wb, unsigned short* __restrict__ ain_wb,
    unsigned short* __restrict__ aout_wb, unsigned short* __restrict__ lin1_wb,
    unsigned short* __restrict__ lin2_wb)
{
  int t = blockIdx.x * 256 + threadIdx.x;
  if (t < 208 * 768) {
    int n = t / 768, k = t - n * 768;
    fc1_wb[t] = f2bf((n < 200) ? fc1_w[n * 768 + k] : 0.f);
    return;
  }
  t -= 208 * 768;
  if (t < 608 * 224) {
    int n = t / 224, k = t - n * 224;
    ain_wb[t] = f2bf((n < 600 && k < 200) ? ain_w[n * 200 + k] : 0.f);
    return;
  }
  t -= 608 * 224;
  if (t < 208 * 224) {
    int n = t / 224, k = t - n * 224;
    aout_wb[t] = f2bf((n < 200 && k < 200) ? aout_w[n * 200 + k] : 0.f);
    return;
  }
  t -= 208 * 224;
  if (t < 208 * 224) {
    int n = t / 224, k = t - n * 224;
    lin1_wb[t] = f2bf((n < 200 && k < 200) ? lin1_w[n * 200 + k] : 0.f);
    return;
  }
  t -= 208 * 224;
  if (t < 208 * 224) {
    int n = t / 224, k = t - n * 224;
    lin2_wb[t] = f2bf((n < 200 && k < 200) ? lin2_w[n * 200 + k] : 0.f);
  }
}

// ---------------------------------------------------------------------------
// Mega-kernel: one block per batch b runs the entire transformer stack.
// Scratch per block (global ws, L2-hot). LDS for scores/P and final y2.
// Rows 33..47 of all M-padded buffers are don't-care (may be garbage/NaN) —
// every consumer masks by index; P rows>=33 are explicitly zeroed so NaN
// never crosses into real rows.
// ---------------------------------------------------------------------------
#define SB_XF   0                 // x_f32 [48][208] f32
#define SB_XB   39936             // x_bf  [48][224] bf16
#define SB_QB   61440             // q_bf  [48][224]
#define SB_KB   82944             // k_bf  [48][224]
#define SB_VT   104448            // vt_bf [208][64]
#define SB_AB   131072            // att_bf[48][224]
#define SB_YF   152576            // y_f32 [48][208] f32
#define SB_YB   192512            // y_bf  [48][224]
#define SB_F1   214016            // f1_bf [48][224]
#define SB_BLK  235520

__global__ __launch_bounds__(512) void mega_kernel(
    const unsigned short* __restrict__ pooled,
    const unsigned short* __restrict__ fc1_wb, const float* __restrict__ fc1_b,
    const unsigned short* __restrict__ ain_wb, const float* __restrict__ ain_b,
    const unsigned short* __restrict__ aout_wb, const float* __restrict__ aout_b,
    const unsigned short* __restrict__ lin1_wb, const float* __restrict__ lin1_b,
    const unsigned short* __restrict__ lin2_wb, const float* __restrict__ lin2_b,
    const float* __restrict__ ln1_g, const float* __restrict__ ln1_b,
    const float* __restrict__ ln2_g, const float* __restrict__ ln2_b,
    const float* __restrict__ fc_w, const float* __restrict__ fc_b,
    char* __restrict__ scratch, float* __restrict__ out)
{
  const int b = blockIdx.x, tid = threadIdx.x;
  const int wv = tid >> 6, lane = tid & 63;
  const int col = lane & 15, quad = lane >> 4;
  const int koff = quad * 8;

  char* sb = scratch + (size_t)b * SB_BLK;
  float*          x_f32  = (float*)(sb + SB_XF);
  unsigned short* x_bf   = (unsigned short*)(sb + SB_XB);
  unsigned short* q_bf   = (unsigned short*)(sb + SB_QB);
  unsigned short* k_bf   = (unsigned short*)(sb + SB_KB);
  unsigned short* vt_bf  = (unsigned short*)(sb + SB_VT);
  unsigned short* att_bf = (unsigned short*)(sb + SB_AB);
  float*          y_f32  = (float*)(sb + SB_YF);
  unsigned short* y_bf   = (unsigned short*)(sb + SB_YB);
  unsigned short* f1_bf  = (unsigned short*)(sb + SB_F1);

  __shared__ __align__(16) char smem[27456];
  float*          sc = (float*)smem;                      // [48][52] f32
  unsigned short* Pb = (unsigned short*)(smem + 9984);    // [48][72] bf16
  float*          y2 = (float*)smem;                      // [33][208] f32 (aliases sc/Pb, later)

  // ---- Z: zero pad columns (ws is poisoned 0xAA every launch) ----
  {
    unsigned short* bufs[6] = {x_bf, q_bf, k_bf, att_bf, y_bf, f1_bf};
    const uint4 z4 = make_uint4(0, 0, 0, 0);
    for (int u = tid; u < 6 * 48 * 4; u += 512) {         // cols 192..223, 16B chunks
      int bi = u / (48 * 4), rem = u - bi * (48 * 4);
      int row = rem >> 2, c = rem & 3;
      *(uint4*)(bufs[bi] + row * 224 + 192 + c * 8) = z4;
    }
    for (int u = tid; u < 208 * 4; u += 512) {            // vt cols 32..63
      int row = u >> 2, c = u & 3;
      *(uint4*)(vt_bf + row * 64 + 32 + c * 8) = z4;
    }
  }
  __syncthreads();

  // ---- S1: x = pooled[b] @ fc1_w^T + b   (M=48, N=208, K=768) ----
  {
    const unsigned short* Ab = pooled + (size_t)b * SS * DD;
    for (int t = wv; t < 3 * 13; t += 8) {
      int mt = t / 13, nt = t - mt * 13;
      int m0 = mt * 16, n0 = nt * 16;
      f4_t acc = mfma_tile<24>(Ab + (size_t)(m0 + col) * DD + koff,
                               fc1_wb + (size_t)(n0 + col) * DD + koff);
      int gn = n0 + col;
      if (gn < DM) {
        float bv = fc1_b[gn];
#pragma unroll
        for (int r = 0; r < 4; ++r) {
          int gm = m0 + quad * 4 + r;
          float v = acc[r] + bv;
          x_f32[gm * 208 + gn] = v;
          x_bf[gm * 224 + gn] = f2bf(v);
        }
      }
    }
  }
  __syncthreads();

  // ---- S2: qkv = x @ ain_w^T + b  (N=608, K=224); route to q/k/vt ----
  for (int t = wv; t < 3 * 38; t += 8) {
    int mt = t / 38, nt = t - mt * 38;
    int m0 = mt * 16, n0 = nt * 16;
    f4_t acc = mfma_tile<7>(x_bf + (m0 + col) * 224 + koff,
                            ain_wb + (size_t)(n0 + col) * 224 + koff);
    int gn = n0 + col;
    if (gn < 600) {
      float bv = ain_b[gn];
#pragma unroll
      for (int r = 0; r < 4; ++r) {
        int gm = m0 + quad * 4 + r;
        unsigned short bfv = f2bf(acc[r] + bv);
        if (gn < 200)      q_bf[gm * 224 + gn] = bfv;
        else if (gn < 400) k_bf[gm * 224 + (gn - 200)] = bfv;
        else if (gm < SS)  vt_bf[(gn - 400) * 64 + gm] = bfv;   // V^T
      }
    }
  }
  __syncthreads();

  // ---- S3: scores = Q @ K^T / sqrt(DM)  (M=48, N=48, K=224) -> LDS ----
  for (int t = wv; t < 9; t += 8) {
    int mt = t / 3, nt = t - mt * 3;
    int m0 = mt * 16, n0 = nt * 16;
    f4_t acc = mfma_tile<7>(q_bf + (m0 + col) * 224 + koff,
                            k_bf + (n0 + col) * 224 + koff);
    int gn = n0 + col;
#pragma unroll
    for (int r = 0; r < 4; ++r)
      sc[(m0 + quad * 4 + r) * 52 + gn] = acc[r] * 0.07071067811865475f;
  }
  __syncthreads();

  // ---- S4: row softmax (index-masked to 33) + P -> bf16 A-layout ----
  if (tid < SS) {
    float mx = -1e30f;
    for (int j = 0; j < SS; ++j) mx = fmaxf(mx, sc[tid * 52 + j]);
    float sm = 0.f;
    for (int j = 0; j < SS; ++j) { float e = __expf(sc[tid * 52 + j] - mx); sc[tid * 52 + j] = e; sm += e; }
    float inv = 1.f / sm;
    for (int j = 0; j < SS; ++j) sc[tid * 52 + j] *= inv;
  }
  __syncthreads();
  for (int u = tid; u < 48 * 64; u += 512) {
    int m = u >> 6, k = u & 63;
    Pb[m * 72 + k] = (m < SS && k < SS) ? f2bf(sc[m * 52 + k]) : (unsigned short)0;
  }
  __syncthreads();

  // ---- S5: att = P @ V  (A=Pb in LDS, W=vt_bf; N=208, K=64) ----
  for (int t = wv; t < 3 * 13; t += 8) {
    int mt = t / 13, nt = t - mt * 13;
    int m0 = mt * 16, n0 = nt * 16;
    f4_t acc = mfma_tile<2>((const unsigned short*)(Pb + (m0 + col) * 72 + koff),
                            vt_bf + (n0 + col) * 64 + koff);
    int gn = n0 + col;
    if (gn < DM) {
#pragma unroll
      for (int r = 0; r < 4; ++r)
        att_bf[(m0 + quad * 4 + r) * 224 + gn] = f2bf(acc[r]);
    }
  }
  __syncthreads();

  // ---- S6: y = x + att @ aout_w^T + b ----
  for (int t = wv; t < 3 * 13; t += 8) {
    int mt = t / 13, nt = t - mt * 13;
    int m0 = mt * 16, n0 = nt * 16;
    f4_t acc = mfma_tile<7>(att_bf + (m0 + col) * 224 + koff,
                            aout_wb + (size_t)(n0 + col) * 224 + koff);
    int gn = n0 + col;
    if (gn < DM) {
      float bv = aout_b[gn];
#pragma unroll
      for (int r = 0; r < 4; ++r) {
        int gm = m0 + quad * 4 + r;
        y_f32[gm * 208 + gn] = acc[r] + bv + x_f32[gm * 208 + gn];
      }
    }
  }
  __syncthreads();

  // ---- S7: LN1 (rows 0..32), write y_f32 (normed) + y_bf ----
  for (int r = wv; r < SS; r += 8) {
    float* p = y_f32 + r * 208;
    float vals[4]; float s = 0.f;
#pragma unroll
    for (int i = 0; i < 4; ++i) { int k = lane + 64 * i; vals[i] = (k < DM) ? p[k] : 0.f; s += vals[i]; }
#pragma unroll
    for (int off = 32; off; off >>= 1) s += __shfl_xor(s, off);
    float mean = s * (1.f / DM);
    float vs = 0.f;
#pragma unroll
    for (int i = 0; i < 4; ++i) { int k = lane + 64 * i; if (k < DM) { float d = vals[i] - mean; vs += d * d; } }
#pragma unroll
    for (int off = 32; off; off >>= 1) vs += __shfl_xor(vs, off);
    float rstd = rsqrtf(vs * (1.f / DM) + 1e-5f);
#pragma unroll
    for (int i = 0; i < 4; ++i) {
      int k = lane + 64 * i;
      if (k < DM) {
        float o = (vals[i] - mean) * rstd * ln1_g[k] + ln1_b[k];
        p[k] = o;
        y_bf[r * 224 + k] = f2bf(o);
      }
    }
  }
  __syncthreads();

  // ---- S8: f1 = relu(y @ lin1_w^T + b) ----
  for (int t = wv; t < 3 * 13; t += 8) {
    int mt = t / 13, nt = t - mt * 13;
    int m0 = mt * 16, n0 = nt * 16;
    f4_t acc = mfma_tile<7>(y_bf + (m0 + col) * 224 + koff,
                            lin1_wb + (size_t)(n0 + col) * 224 + koff);
    int gn = n0 + col;
    if (gn < DM) {
      float bv = lin1_b[gn];
#pragma unroll
      for (int r = 0; r < 4; ++r)
        f1_bf[(m0 + quad * 4 + r) * 224 + gn] = f2bf(fmaxf(acc[r] + bv, 0.f));
    }
  }
  __syncthreads();

  // ---- S9: y2 = y + f1 @ lin2_w^T + b  -> LDS (rows<33 only) ----
  for (int t = wv; t < 3 * 13; t += 8) {
    int mt = t / 13, nt = t - mt * 13;
    int m0 = mt * 16, n0 = nt * 16;
    f4_t acc = mfma_tile<7>(f1_bf + (m0 + col) * 224 + koff,
                            lin2_wb + (size_t)(n0 + col) * 224 + koff);
    int gn = n0 + col;
    if (gn < DM) {
      float bv = lin2_b[gn];
#pragma unroll
      for (int r = 0; r < 4; ++r) {
        int gm = m0 + quad * 4 + r;
        if (gm < SS) y2[gm * 208 + gn] = acc[r] + bv + y_f32[gm * 208 + gn];
      }
    }
  }
  __syncthreads();

  // ---- S10: LN2 on y2 (LDS, in place) ----
  for (int r = wv; r < SS; r += 8) {
    float* p = y2 + r * 208;
    float vals[4]; float s = 0.f;
#pragma unroll
    for (int i = 0; i < 4; ++i) { int k = lane + 64 * i; vals[i] = (k < DM) ? p[k] : 0.f; s += vals[i]; }
#pragma unroll
    for (int off = 32; off; off >>= 1) s += __shfl_xor(s, off);
    float mean = s * (1.f / DM);
    float vs = 0.f;
#pragma unroll
    for (int i = 0; i < 4; ++i) { int k = lane + 64 * i; if (k < DM) { float d = vals[i] - mean; vs += d * d; } }
#pragma unroll
    for (int off = 32; off; off >>= 1) vs += __shfl_xor(vs, off);
    float rstd = rsqrtf(vs * (1.f / DM) + 1e-5f);
#pragma unroll
    for (int i = 0; i < 4; ++i) {
      int k = lane + 64 * i;
      if (k < DM) p[k] = (vals[i] - mean) * rstd * ln2_g[k] + ln2_b[k];
    }
  }
  __syncthreads();

  // ---- S11: classifier out[b,j,:] = [y2_0, y2_{1+j}] . fc_w^T + fc_b ----
  for (int j = wv; j < JJ; j += 8) {
    const float* r0 = y2;
    const float* rj = y2 + (1 + j) * 208;
    float a0 = 0.f, a1 = 0.f;
    for (int k = lane; k < DM; k += 64) {
      float u = r0[k], w = rj[k];
      a0 += u * fc_w[k]       + w * fc_w[200 + k];
      a1 += u * fc_w[400 + k] + w * fc_w[600 + k];
    }
#pragma unroll
    for (int off = 32; off; off >>= 1) {
      a0 += __shfl_xor(a0, off);
      a1 += __shfl_xor(a1, off);
    }
    if (lane == 0) {
      out[(b * JJ + j) * 2 + 0] = a0 + fc_b[0];
      out[(b * JJ + j) * 2 + 1] = a1 + fc_b[1];
    }
  }
}

// ---------------------------------------------------------------------------
extern "C" void kernel_launch(void* const* d_in, const int* in_sizes, int n_in,
                              void* d_out, int out_size, void* d_ws, size_t ws_size,
                              hipStream_t stream)
{
  (void)in_sizes; (void)n_in; (void)out_size; (void)ws_size;
  const float* hidden = (const float*)d_in[0];
  const int*   clause = (const int*)d_in[1];
  const float* fc5_w  = (const float*)d_in[2];
  const float* fc1_w  = (const float*)d_in[4];
  const float* fc1_b  = (const float*)d_in[5];
  const float* ain_w  = (const float*)d_in[6];
  const float* ain_b  = (const float*)d_in[7];
  const float* aout_w = (const float*)d_in[8];
  const float* aout_b = (const float*)d_in[9];
  const float* ln1_g  = (const float*)d_in[10];
  const float* ln1_b  = (const float*)d_in[11];
  const float* lin1_w = (const float*)d_in[12];
  const float* lin1_b = (const float*)d_in[13];
  const float* lin2_w = (const float*)d_in[14];
  const float* lin2_b = (const float*)d_in[15];
  const float* ln2_g  = (const float*)d_in[16];
  const float* ln2_b  = (const float*)d_in[17];
  const float* fc_w   = (const float*)d_in[18];
  const float* fc_b   = (const float*)d_in[19];
  float* out = (float*)d_out;

  char* w8 = (char*)d_ws;
  // pooled: [4224][768] bf16 = 6,488,064 B ; then 32 KB guard (OOB reads of
  // the last batch's m-tile land here — poison bytes, finite bf16).
  unsigned short* pooled_bf = (unsigned short*)(w8 + 0);
  char* scratch = w8 + 6520832;                       // 128 * 235,520 B
  size_t wbase = 6520832 + (size_t)NB * SB_BLK;       // = 36,667,392
  unsigned short* fc1_wb  = (unsigned short*)(w8 + wbase);
  unsigned short* ain_wb  = (unsigned short*)(w8 + wbase + 319488);
  unsigned short* aout_wb = (unsigned short*)(w8 + wbase + 591872);
  unsigned short* lin1_wb = (unsigned short*)(w8 + wbase + 685056);
  unsigned short* lin2_wb = (unsigned short*)(w8 + wbase + 778240);

  pool_kernel<<<dim3(NB * SS), 256, 0, stream>>>(hidden, clause, fc5_w, pooled_bf);
  convert_w<<<dim3(1702), 256, 0, stream>>>(fc1_w, ain_w, aout_w, lin1_w, lin2_w,
      fc1_wb, ain_wb, aout_wb, lin1_wb, lin2_wb);
  mega_kernel<<<dim3(NB), 512, 0, stream>>>(pooled_bf,
      fc1_wb, fc1_b, ain_wb, ain_b, aout_wb, aout_b,
      lin1_wb, lin1_b, lin2_wb, lin2_b,
      ln1_g, ln1_b, ln2_g, ln2_b, fc_w, fc_b,
      scratch, out);
}

// Round 4
// 425.090 us; speedup vs baseline: 1.0841x; 1.0841x over previous
//
#include <hip/hip_runtime.h>

#define NB 128
#define LL 512
#define DD 768
#define JJ 32
#define SS 33
#define DM 200

typedef __attribute__((ext_vector_type(8))) short bf8_t;   // 8 bf16 (4 VGPRs)
typedef __attribute__((ext_vector_type(4))) float f4_t;    // MFMA C/D

// per-batch scratch block (bytes)
#define SB_XF   0                 // x_f32 [48][208] f32
#define SB_XB   39936             // x_bf  [48][224] bf16
#define SB_QB   61440             // q_bf  [48][224]
#define SB_KB   82944             // k_bf  [48][224]
#define SB_VT   104448            // vt_bf [208][64]
#define SB_AB   131072            // att_bf[48][224]
#define SB_YF   152576            // y_f32 [48][208] f32
#define SB_YB   192512            // y_bf  [48][224]
#define SB_F1   214016            // f1_bf [48][224]
#define SB_Y2   235520            // y2_f32[48][208] f32
#define SB_BLK  275456

static __device__ __forceinline__ unsigned short f2bf(float f) {
  unsigned u = __float_as_uint(f);
  return (unsigned short)((u + 0x7FFFu + ((u >> 16) & 1u)) >> 16);  // RNE
}

// One 16x16 MFMA tile, K = 32*KS, row-major operands, ptrs pre-offset.
template<int KS>
static __device__ __forceinline__ f4_t mfma_tile(
    const unsigned short* pa, const unsigned short* pw)
{
  f4_t acc = {0.f, 0.f, 0.f, 0.f};
  bf8_t a = *(const bf8_t*)pa;
  bf8_t w = *(const bf8_t*)pw;
#pragma unroll
  for (int s = 1; s < KS; ++s) {
    bf8_t a2 = *(const bf8_t*)(pa + 32 * s);
    bf8_t w2 = *(const bf8_t*)(pw + 32 * s);
    acc = __builtin_amdgcn_mfma_f32_16x16x32_bf16(a, w, acc, 0, 0, 0);
    a = a2; w = w2;
  }
  acc = __builtin_amdgcn_mfma_f32_16x16x32_bf16(a, w, acc, 0, 0, 0);
  return acc;
}

// ---------------------------------------------------------------------------
// Fused per-segment score + softmax + weighted pooling -> bf16 pooled.
// ---------------------------------------------------------------------------
__global__ __launch_bounds__(256) void pool_kernel(
    const float* __restrict__ hidden, const int* __restrict__ clause,
    const float* __restrict__ fc5w, unsigned short* __restrict__ pooled_bf)
{
  int blk = blockIdx.x;          // b*33 + s
  int b = blk / SS;
  int s = blk - b * SS;
  int t0 = (s == 0) ? 0 : clause[b * JJ + s - 1];
  int t1 = (s == JJ) ? LL : clause[b * JJ + s];
  int nt = t1 - t0;
  if (nt > 64) nt = 64;
  if (nt < 1) nt = 1;

  __shared__ float wsm[64];
  int tid = threadIdx.x;
  int wave = tid >> 6, lane = tid & 63;

  const float4* w4 = (const float4*)fc5w;
  for (int t = t0 + wave; t < t0 + nt; t += 4) {
    const float4* hp = (const float4*)(hidden + ((long long)b * LL + t) * DD);
    float acc = 0.f;
#pragma unroll
    for (int i = 0; i < 3; ++i) {
      float4 h = hp[lane + 64 * i];
      float4 w = w4[lane + 64 * i];
      acc += h.x * w.x + h.y * w.y + h.z * w.z + h.w * w.w;
    }
#pragma unroll
    for (int off = 32; off; off >>= 1) acc += __shfl_xor(acc, off);
    if (lane == 0) wsm[t - t0] = acc;
  }
  __syncthreads();

  if (wave == 0) {
    float v = (lane < nt) ? wsm[lane] : -__builtin_inff();
    float mx = v;
#pragma unroll
    for (int off = 32; off; off >>= 1) mx = fmaxf(mx, __shfl_xor(mx, off));
    float e = (lane < nt) ? __expf(v - mx) : 0.f;
    float sm = e;
#pragma unroll
    for (int off = 32; off; off >>= 1) sm += __shfl_xor(sm, off);
    if (lane < nt) wsm[lane] = e / sm;
  }
  __syncthreads();

  if (tid < 192) {
    const float4* base = (const float4*)(hidden + ((long long)b * LL + t0) * DD);
    float4 acc = make_float4(0.f, 0.f, 0.f, 0.f);
#pragma unroll 4
    for (int t = 0; t < nt; ++t) {
      float w = wsm[t];
      float4 h = base[t * 192 + tid];
      acc.x = fmaf(w, h.x, acc.x); acc.y = fmaf(w, h.y, acc.y);
      acc.z = fmaf(w, h.z, acc.z); acc.w = fmaf(w, h.w, acc.w);
    }
    ushort4 o;
    o.x = f2bf(acc.x); o.y = f2bf(acc.y); o.z = f2bf(acc.z); o.w = f2bf(acc.w);
    *(ushort4*)(pooled_bf + (long long)blk * DD + tid * 4) = o;
  }
}

// ---------------------------------------------------------------------------
// Convert + pad weights fp32 -> bf16, AND zero the pad columns of all
// per-batch bf16 scratch buffers (cols 192..223; vt cols 32..63).
// ---------------------------------------------------------------------------
__global__ __launch_bounds__(256) void convert_w(
    const float* __restrict__ fc1_w, const float* __restrict__ ain_w,
    const float* __restrict__ aout_w, const float* __restrict__ lin1_w,
    const float* __restrict__ lin2_w,
    unsigned short* __restrict__ fc1_wb, unsigned short* __restrict__ ain_wb,
    unsigned short* __restrict__ aout_wb, unsigned short* __restrict__ lin1_wb,
    unsigned short* __restrict__ lin2_wb, char* __restrict__ scratch)
{
  int t = blockIdx.x * 256 + threadIdx.x;
  if (t < 208 * 768) {
    int n = t / 768, k = t - n * 768;
    fc1_wb[t] = f2bf((n < 200) ? fc1_w[n * 768 + k] : 0.f);
    return;
  }
  t -= 208 * 768;
  if (t < 608 * 224) {
    int n = t / 224, k = t - n * 224;
    ain_wb[t] = f2bf((n < 600 && k < 200) ? ain_w[n * 200 + k] : 0.f);
    return;
  }
  t -= 608 * 224;
  if (t < 208 * 224) {
    int n = t / 224, k = t - n * 224;
    aout_wb[t] = f2bf((n < 200 && k < 200) ? aout_w[n * 200 + k] : 0.f);
    return;
  }
  t -= 208 * 224;
  if (t < 208 * 224) {
    int n = t / 224, k = t - n * 224;
    lin1_wb[t] = f2bf((n < 200 && k < 200) ? lin1_w[n * 200 + k] : 0.f);
    return;
  }
  t -= 208 * 224;
  if (t < 208 * 224) {
    int n = t / 224, k = t - n * 224;
    lin2_wb[t] = f2bf((n < 200 && k < 200) ? lin2_w[n * 200 + k] : 0.f);
    return;
  }
  t -= 208 * 224;
  if (t < NB * 1984) {            // pad-zero segment, one uint4 per thread
    int b = t / 1984, r = t - b * 1984;
    char* sb = scratch + (size_t)b * SB_BLK;
    const uint4 z = make_uint4(0, 0, 0, 0);
    if (r < 1152) {               // 6 bufs x 48 rows x 4 chunks (cols 192..223)
      int bi = r / 192, rr = r - bi * 192;
      int row = rr >> 2, c = rr & 3;
      int off = (bi < 3) ? (SB_XB + bi * 21504)
                         : (bi == 3 ? SB_AB : (bi == 4 ? SB_YB : SB_F1));
      *(uint4*)((unsigned short*)(sb + off) + row * 224 + 192 + c * 8) = z;
    } else {                      // vt 208 rows x 4 chunks (cols 32..63)
      int rr = r - 1152;
      int row = rr >> 2, c = rr & 3;
      *(uint4*)((unsigned short*)(sb + SB_VT) + row * 64 + 32 + c * 8) = z;
    }
  }
}

// ---------------------------------------------------------------------------
// K1: x = pooled[b] @ fc1_w^T + b   (per-batch M=48, N=208, K=768)
// grid: 128 batches x 39 tiles, one tile per wave.
// ---------------------------------------------------------------------------
__global__ __launch_bounds__(256) void k_fc1(
    const unsigned short* __restrict__ pooled,
    const unsigned short* __restrict__ Wb, const float* __restrict__ bias,
    char* __restrict__ scratch)
{
  int gw = blockIdx.x * 4 + (threadIdx.x >> 6);
  int lane = threadIdx.x & 63;
  int b = gw / 39, t = gw - b * 39;
  int mt = t / 13, nt = t - mt * 13;
  int m0 = mt * 16, n0 = nt * 16;
  int col = lane & 15, quad = lane >> 4, koff = quad * 8;

  char* sb = scratch + (size_t)b * SB_BLK;
  float*          x_f32 = (float*)(sb + SB_XF);
  unsigned short* x_bf  = (unsigned short*)(sb + SB_XB);

  const unsigned short* Ab = pooled + (size_t)b * SS * DD;
  f4_t acc = mfma_tile<24>(Ab + (size_t)(m0 + col) * DD + koff,
                           Wb + (size_t)(n0 + col) * DD + koff);
  int gn = n0 + col;
  if (gn < DM) {
    float bv = bias[gn];
#pragma unroll
    for (int r = 0; r < 4; ++r) {
      int gm = m0 + quad * 4 + r;
      float v = acc[r] + bv;
      x_f32[gm * 208 + gn] = v;
      x_bf[gm * 224 + gn] = f2bf(v);
    }
  }
}

// ---------------------------------------------------------------------------
// K2: qkv = x @ ain_w^T + b  (N=608, K=224); route to q/k/vt per batch.
// grid: 128 x 114 tiles.
// ---------------------------------------------------------------------------
__global__ __launch_bounds__(256) void k_qkv(
    const unsigned short* __restrict__ Wb, const float* __restrict__ bias,
    char* __restrict__ scratch)
{
  int gw = blockIdx.x * 4 + (threadIdx.x >> 6);
  int lane = threadIdx.x & 63;
  int b = gw / 114, t = gw - b * 114;
  int mt = t / 38, nt = t - mt * 38;
  int m0 = mt * 16, n0 = nt * 16;
  int col = lane & 15, quad = lane >> 4, koff = quad * 8;

  char* sb = scratch + (size_t)b * SB_BLK;
  const unsigned short* x_bf = (const unsigned short*)(sb + SB_XB);
  unsigned short* q_bf  = (unsigned short*)(sb + SB_QB);
  unsigned short* k_bf  = (unsigned short*)(sb + SB_KB);
  unsigned short* vt_bf = (unsigned short*)(sb + SB_VT);

  f4_t acc = mfma_tile<7>(x_bf + (m0 + col) * 224 + koff,
                          Wb + (size_t)(n0 + col) * 224 + koff);
  int gn = n0 + col;
  if (gn < 600) {
    float bv = bias[gn];
#pragma unroll
    for (int r = 0; r < 4; ++r) {
      int gm = m0 + quad * 4 + r;
      unsigned short bfv = f2bf(acc[r] + bv);
      if (gn < 200)      q_bf[gm * 224 + gn] = bfv;
      else if (gn < 400) k_bf[gm * 224 + (gn - 200)] = bfv;
      else if (gm < SS)  vt_bf[(gn - 400) * 64 + gm] = bfv;   // V^T
    }
  }
}

// ---------------------------------------------------------------------------
// K3: fused attention per batch: sc = QK^T/sqrt(DM), softmax, att = P V.
// 128 blocks x 512 threads.
// ---------------------------------------------------------------------------
__global__ __launch_bounds__(512) void k_attn(char* __restrict__ scratch)
{
  const int b = blockIdx.x, tid = threadIdx.x;
  const int wv = tid >> 6, lane = tid & 63;
  const int col = lane & 15, quad = lane >> 4, koff = quad * 8;

  char* sb = scratch + (size_t)b * SB_BLK;
  const unsigned short* q_bf  = (const unsigned short*)(sb + SB_QB);
  const unsigned short* k_bf  = (const unsigned short*)(sb + SB_KB);
  const unsigned short* vt_bf = (const unsigned short*)(sb + SB_VT);
  unsigned short* att_bf = (unsigned short*)(sb + SB_AB);

  __shared__ __align__(16) char smem[16896];
  float*          sc = (float*)smem;                      // [48][52]
  unsigned short* Pb = (unsigned short*)(smem + 9984);    // [48][72]

  for (int t = wv; t < 9; t += 8) {
    int mt = t / 3, nt = t - mt * 3;
    int m0 = mt * 16, n0 = nt * 16;
    f4_t acc = mfma_tile<7>(q_bf + (m0 + col) * 224 + koff,
                            k_bf + (n0 + col) * 224 + koff);
    int gn = n0 + col;
#pragma unroll
    for (int r = 0; r < 4; ++r)
      sc[(m0 + quad * 4 + r) * 52 + gn] = acc[r] * 0.07071067811865475f;
  }
  __syncthreads();

  if (tid < SS) {
    float mx = -1e30f;
    for (int j = 0; j < SS; ++j) mx = fmaxf(mx, sc[tid * 52 + j]);
    float sm = 0.f;
    for (int j = 0; j < SS; ++j) { float e = __expf(sc[tid * 52 + j] - mx); sc[tid * 52 + j] = e; sm += e; }
    float inv = 1.f / sm;
    for (int j = 0; j < SS; ++j) sc[tid * 52 + j] *= inv;
  }
  __syncthreads();
  for (int u = tid; u < 48 * 64; u += 512) {
    int m = u >> 6, k = u & 63;
    Pb[m * 72 + k] = (m < SS && k < SS) ? f2bf(sc[m * 52 + k]) : (unsigned short)0;
  }
  __syncthreads();

  for (int t = wv; t < 3 * 13; t += 8) {
    int mt = t / 13, nt = t - mt * 13;
    int m0 = mt * 16, n0 = nt * 16;
    f4_t acc = mfma_tile<2>(Pb + (m0 + col) * 72 + koff,
                            vt_bf + (n0 + col) * 64 + koff);
    int gn = n0 + col;
    if (gn < DM) {
#pragma unroll
      for (int r = 0; r < 4; ++r)
        att_bf[(m0 + quad * 4 + r) * 224 + gn] = f2bf(acc[r]);
    }
  }
}

// ---------------------------------------------------------------------------
// K4/K6: C = A @ W^T + bias + res, then LayerNorm rows -> outF (+optional bf16).
// One block = one 16-row m-tile of one batch. grid 384 x 256.
// Byte offsets select per-batch buffers.
// ---------------------------------------------------------------------------
__global__ __launch_bounds__(256) void k_gemm_ln(
    const unsigned short* __restrict__ Wb, const float* __restrict__ bias,
    const float* __restrict__ g, const float* __restrict__ be,
    char* __restrict__ scratch,
    int offA, int offRes, int offOutF, int offOutB)
{
  const int b = blockIdx.x / 3, mt = blockIdx.x % 3;
  const int m0 = mt * 16;
  const int tid = threadIdx.x, wv = tid >> 6, lane = tid & 63;
  const int col = lane & 15, quad = lane >> 4, koff = quad * 8;

  char* sb = scratch + (size_t)b * SB_BLK;
  const unsigned short* A = (const unsigned short*)(sb + offA);
  const float* res = (const float*)(sb + offRes);
  float* outF = (float*)(sb + offOutF);
  unsigned short* outB = (offOutB >= 0) ? (unsigned short*)(sb + offOutB) : (unsigned short*)0;

  __shared__ float tileC[16][211];

  for (int t = wv; t < 13; t += 4) {
    int n0 = t * 16;
    f4_t acc = mfma_tile<7>(A + (m0 + col) * 224 + koff,
                            Wb + (size_t)(n0 + col) * 224 + koff);
    int gn = n0 + col;
    float bv = (gn < DM) ? bias[gn] : 0.f;
#pragma unroll
    for (int r = 0; r < 4; ++r) {
      int row = quad * 4 + r;
      float v = acc[r] + bv;
      if (gn < DM) v += res[(m0 + row) * 208 + gn];
      tileC[row][gn] = v;
    }
  }
  __syncthreads();

  for (int r = wv; r < 16; r += 4) {
    float* p = &tileC[r][0];
    float vals[4]; float s = 0.f;
#pragma unroll
    for (int i = 0; i < 4; ++i) { int k = lane + 64 * i; vals[i] = (k < DM) ? p[k] : 0.f; s += vals[i]; }
#pragma unroll
    for (int off = 32; off; off >>= 1) s += __shfl_xor(s, off);
    float mean = s * (1.f / DM);
    float vs = 0.f;
#pragma unroll
    for (int i = 0; i < 4; ++i) { int k = lane + 64 * i; if (k < DM) { float d = vals[i] - mean; vs += d * d; } }
#pragma unroll
    for (int off = 32; off; off >>= 1) vs += __shfl_xor(vs, off);
    float rstd = rsqrtf(vs * (1.f / DM) + 1e-5f);
    int grow = m0 + r;
#pragma unroll
    for (int i = 0; i < 4; ++i) {
      int k = lane + 64 * i;
      if (k < DM) {
        float o = (vals[i] - mean) * rstd * g[k] + be[k];
        outF[grow * 208 + k] = o;
        if (outB) outB[grow * 224 + k] = f2bf(o);
      }
    }
  }
}

// ---------------------------------------------------------------------------
// K5: f1 = relu(y @ lin1_w^T + b). grid 128 x 39 tiles.
// ---------------------------------------------------------------------------
__global__ __launch_bounds__(256) void k_ffn1(
    const unsigned short* __restrict__ Wb, const float* __restrict__ bias,
    char* __restrict__ scratch)
{
  int gw = blockIdx.x * 4 + (threadIdx.x >> 6);
  int lane = threadIdx.x & 63;
  int b = gw / 39, t = gw - b * 39;
  int mt = t / 13, nt = t - mt * 13;
  int m0 = mt * 16, n0 = nt * 16;
  int col = lane & 15, quad = lane >> 4, koff = quad * 8;

  char* sb = scratch + (size_t)b * SB_BLK;
  const unsigned short* y_bf = (const unsigned short*)(sb + SB_YB);
  unsigned short* f1_bf = (unsigned short*)(sb + SB_F1);

  f4_t acc = mfma_tile<7>(y_bf + (m0 + col) * 224 + koff,
                          Wb + (size_t)(n0 + col) * 224 + koff);
  int gn = n0 + col;
  if (gn < DM) {
    float bv = bias[gn];
#pragma unroll
    for (int r = 0; r < 4; ++r)
      f1_bf[(m0 + quad * 4 + r) * 224 + gn] = f2bf(fmaxf(acc[r] + bv, 0.f));
  }
}

// ---------------------------------------------------------------------------
// K7: classifier. One wave per (b, j).
// ---------------------------------------------------------------------------
__global__ __launch_bounds__(256) void k_cls(
    const char* __restrict__ scratch, const float* __restrict__ fcw,
    const float* __restrict__ fcb, float* __restrict__ out)
{
  int gw = blockIdx.x * 4 + (threadIdx.x >> 6);   // b*32 + j
  int lane = threadIdx.x & 63;
  int b = gw >> 5, j = gw & 31;
  const float* y2 = (const float*)(scratch + (size_t)b * SB_BLK + SB_Y2);
  const float* r0 = y2;
  const float* rj = y2 + (1 + j) * 208;
  float a0 = 0.f, a1 = 0.f;
  for (int k = lane; k < DM; k += 64) {
    float u = r0[k], w = rj[k];
    a0 += u * fcw[k]       + w * fcw[200 + k];
    a1 += u * fcw[400 + k] + w * fcw[600 + k];
  }
#pragma unroll
  for (int off = 32; off; off >>= 1) {
    a0 += __shfl_xor(a0, off);
    a1 += __shfl_xor(a1, off);
  }
  if (lane == 0) {
    out[gw * 2 + 0] = a0 + fcb[0];
    out[gw * 2 + 1] = a1 + fcb[1];
  }
}

// ---------------------------------------------------------------------------
extern "C" void kernel_launch(void* const* d_in, const int* in_sizes, int n_in,
                              void* d_out, int out_size, void* d_ws, size_t ws_size,
                              hipStream_t stream)
{
  (void)in_sizes; (void)n_in; (void)out_size; (void)ws_size;
  const float* hidden = (const float*)d_in[0];
  const int*   clause = (const int*)d_in[1];
  const float* fc5_w  = (const float*)d_in[2];
  const float* fc1_w  = (const float*)d_in[4];
  const float* fc1_b  = (const float*)d_in[5];
  const float* ain_w  = (const float*)d_in[6];
  const float* ain_b  = (const float*)d_in[7];
  const float* aout_w = (const float*)d_in[8];
  const float* aout_b = (const float*)d_in[9];
  const float* ln1_g  = (const float*)d_in[10];
  const float* ln1_b  = (const float*)d_in[11];
  const float* lin1_w = (const float*)d_in[12];
  const float* lin1_b = (const float*)d_in[13];
  const float* lin2_w = (const float*)d_in[14];
  const float* lin2_b = (const float*)d_in[15];
  const float* ln2_g  = (const float*)d_in[16];
  const float* ln2_b  = (const float*)d_in[17];
  const float* fc_w   = (const float*)d_in[18];
  const float* fc_b   = (const float*)d_in[19];
  float* out = (float*)d_out;

  char* w8 = (char*)d_ws;
  unsigned short* pooled_bf = (unsigned short*)(w8 + 0);  // [4224][768] + guard
  char* scratch = w8 + 6520832;                           // 128 * SB_BLK
  size_t wbase = 6520832 + (size_t)NB * SB_BLK;           // 41,779,200
  unsigned short* fc1_wb  = (unsigned short*)(w8 + wbase);
  unsigned short* ain_wb  = (unsigned short*)(w8 + wbase + 319488);
  unsigned short* aout_wb = (unsigned short*)(w8 + wbase + 591872);
  unsigned short* lin1_wb = (unsigned short*)(w8 + wbase + 685056);
  unsigned short* lin2_wb = (unsigned short*)(w8 + wbase + 778240);

  convert_w<<<dim3(2694), 256, 0, stream>>>(fc1_w, ain_w, aout_w, lin1_w, lin2_w,
      fc1_wb, ain_wb, aout_wb, lin1_wb, lin2_wb, scratch);
  pool_kernel<<<dim3(NB * SS), 256, 0, stream>>>(hidden, clause, fc5_w, pooled_bf);
  k_fc1<<<dim3(NB * 39 / 4), 256, 0, stream>>>(pooled_bf, fc1_wb, fc1_b, scratch);
  k_qkv<<<dim3(NB * 114 / 4), 256, 0, stream>>>(ain_wb, ain_b, scratch);
  k_attn<<<dim3(NB), 512, 0, stream>>>(scratch);
  k_gemm_ln<<<dim3(NB * 3), 256, 0, stream>>>(aout_wb, aout_b, ln1_g, ln1_b,
      scratch, SB_AB, SB_XF, SB_YF, SB_YB);
  k_ffn1<<<dim3(NB * 39 / 4), 256, 0, stream>>>(lin1_wb, lin1_b, scratch);
  k_gemm_ln<<<dim3(NB * 3), 256, 0, stream>>>(lin2_wb, lin2_b, ln2_g, ln2_b,
      scratch, SB_F1, SB_YF, SB_Y2, -1);
  k_cls<<<dim3(1024), 256, 0, stream>>>(scratch, fc_w, fc_b, out);
}

// Round 5
// 397.023 us; speedup vs baseline: 1.1608x; 1.0707x over previous
//
#include <hip/hip_runtime.h>

#define NB 128
#define LL 512
#define DD 768
#define JJ 32
#define SS 33
#define DM 200

typedef __attribute__((ext_vector_type(8))) short bf8_t;   // 8 bf16 (4 VGPRs)
typedef __attribute__((ext_vector_type(4))) float f4_t;    // MFMA C/D

// per-batch scratch block (bytes) — only XF/QB/KB/VT/AB/Y2 used now
#define SB_XF   0                 // x_f32 [48][208] f32
#define SB_QB   61440             // q_bf  [48][224]
#define SB_KB   82944             // k_bf  [48][224]
#define SB_VT   104448            // vt_bf [208][64]
#define SB_AB   131072            // att_bf[48][224]
#define SB_Y2   235520            // y2_f32[48][208] f32
#define SB_BLK  275456

static __device__ __forceinline__ unsigned short f2bf(float f) {
  unsigned u = __float_as_uint(f);
  return (unsigned short)((u + 0x7FFFu + ((u >> 16) & 1u)) >> 16);  // RNE
}

// One 16x16 MFMA tile, K = 32*KS, row-major operands, ptrs pre-offset.
template<int KS>
static __device__ __forceinline__ f4_t mfma_tile(
    const unsigned short* pa, const unsigned short* pw)
{
  f4_t acc = {0.f, 0.f, 0.f, 0.f};
  bf8_t a = *(const bf8_t*)pa;
  bf8_t w = *(const bf8_t*)pw;
#pragma unroll
  for (int s = 1; s < KS; ++s) {
    bf8_t a2 = *(const bf8_t*)(pa + 32 * s);
    bf8_t w2 = *(const bf8_t*)(pw + 32 * s);
    acc = __builtin_amdgcn_mfma_f32_16x16x32_bf16(a, w, acc, 0, 0, 0);
    a = a2; w = w2;
  }
  acc = __builtin_amdgcn_mfma_f32_16x16x32_bf16(a, w, acc, 0, 0, 0);
  return acc;
}

// LDS-A variant: same but A pointer is LDS (addrspace inferred via generic)
template<int KS, int LDA>
static __device__ __forceinline__ f4_t mfma_tile_lds(
    const unsigned short* pa, const unsigned short* pw)
{
  f4_t acc = {0.f, 0.f, 0.f, 0.f};
#pragma unroll
  for (int s = 0; s < KS; ++s) {
    bf8_t a = *(const bf8_t*)(pa + 32 * s);
    bf8_t w = *(const bf8_t*)(pw + 32 * s);
    acc = __builtin_amdgcn_mfma_f32_16x16x32_bf16(a, w, acc, 0, 0, 0);
  }
  return acc;
}

// ---------------------------------------------------------------------------
// PC kernel: blocks [0, 4224) = fused pool (512 thr); blocks [4224, 5427) =
// weight convert + scratch pad-zero.
// ---------------------------------------------------------------------------
__global__ __launch_bounds__(512) void pc_kernel(
    const float* __restrict__ hidden, const int* __restrict__ clause,
    const float* __restrict__ fc5w, unsigned short* __restrict__ pooled_bf,
    const float* __restrict__ fc1_w, const float* __restrict__ ain_w,
    const float* __restrict__ aout_w, const float* __restrict__ lin1_w,
    const float* __restrict__ lin2_w,
    unsigned short* __restrict__ fc1_wb, unsigned short* __restrict__ ain_wb,
    unsigned short* __restrict__ aout_wb, unsigned short* __restrict__ lin1_wb,
    unsigned short* __restrict__ lin2_wb, char* __restrict__ scratch)
{
  const int tid = threadIdx.x;
  if (blockIdx.x >= NB * SS) {
    // -------- convert + pad-zero part --------
    int t = (blockIdx.x - NB * SS) * 512 + tid;
    if (t < 208 * 768) {
      int n = t / 768, k = t - n * 768;
      fc1_wb[t] = f2bf((n < 200) ? fc1_w[n * 768 + k] : 0.f);
      return;
    }
    t -= 208 * 768;
    if (t < 608 * 224) {
      int n = t / 224, k = t - n * 224;
      ain_wb[t] = f2bf((n < 600 && k < 200) ? ain_w[n * 200 + k] : 0.f);
      return;
    }
    t -= 608 * 224;
    if (t < 208 * 224) {
      int n = t / 224, k = t - n * 224;
      aout_wb[t] = f2bf((n < 200 && k < 200) ? aout_w[n * 200 + k] : 0.f);
      return;
    }
    t -= 208 * 224;
    if (t < 208 * 224) {
      int n = t / 224, k = t - n * 224;
      lin1_wb[t] = f2bf((n < 200 && k < 200) ? lin1_w[n * 200 + k] : 0.f);
      return;
    }
    t -= 208 * 224;
    if (t < 208 * 224) {
      int n = t / 224, k = t - n * 224;
      lin2_wb[t] = f2bf((n < 200 && k < 200) ? lin2_w[n * 200 + k] : 0.f);
      return;
    }
    t -= 208 * 224;
    if (t < NB * 1408) {          // pad-zero: QB/KB/AB cols 192-223, VT cols 32-63
      int b = t / 1408, r = t - b * 1408;
      char* sb = scratch + (size_t)b * SB_BLK;
      const uint4 z = make_uint4(0, 0, 0, 0);
      if (r < 576) {
        int bi = r / 192, rr = r - bi * 192;
        int row = rr >> 2, c = rr & 3;
        int off = (bi == 0) ? SB_QB : (bi == 1 ? SB_KB : SB_AB);
        *(uint4*)((unsigned short*)(sb + off) + row * 224 + 192 + c * 8) = z;
      } else {
        int rr = r - 576;
        int row = rr >> 2, c = rr & 3;
        *(uint4*)((unsigned short*)(sb + SB_VT) + row * 64 + 32 + c * 8) = z;
      }
    }
    return;
  }

  // -------- pool part: block = (b, s) --------
  int blk = blockIdx.x;
  int b = blk / SS;
  int s = blk - b * SS;
  int t0 = (s == 0) ? 0 : clause[b * JJ + s - 1];
  int t1 = (s == JJ) ? LL : clause[b * JJ + s];
  int nt = t1 - t0;
  if (nt > 64) nt = 64;
  if (nt < 1) nt = 1;

  __shared__ float wsm[64];
  int wave = tid >> 6, lane = tid & 63;

  // phase 1: scores (8 waves, one token each per iter)
  const float4* w4 = (const float4*)fc5w;
  for (int t = t0 + wave; t < t0 + nt; t += 8) {
    const float4* hp = (const float4*)(hidden + ((long long)b * LL + t) * DD);
    float acc = 0.f;
#pragma unroll
    for (int i = 0; i < 3; ++i) {
      float4 h = hp[lane + 64 * i];
      float4 w = w4[lane + 64 * i];
      acc += h.x * w.x + h.y * w.y + h.z * w.z + h.w * w.w;
    }
#pragma unroll
    for (int off = 32; off; off >>= 1) acc += __shfl_xor(acc, off);
    if (lane == 0) wsm[t - t0] = acc;
  }
  __syncthreads();

  // phase 2: segment softmax (wave 0)
  if (wave == 0) {
    float v = (lane < nt) ? wsm[lane] : -__builtin_inff();
    float mx = v;
#pragma unroll
    for (int off = 32; off; off >>= 1) mx = fmaxf(mx, __shfl_xor(mx, off));
    float e = (lane < nt) ? __expf(v - mx) : 0.f;
    float sm = e;
#pragma unroll
    for (int off = 32; off; off >>= 1) sm += __shfl_xor(sm, off);
    if (lane < nt) wsm[lane] = e / sm;
  }
  __syncthreads();

  // phase 3: weighted sum, 384 lanes x float2
  if (tid < 384) {
    const float2* base = (const float2*)(hidden + ((long long)b * LL + t0) * DD);
    float2 acc = make_float2(0.f, 0.f);
#pragma unroll 4
    for (int t = 0; t < nt; ++t) {
      float w = wsm[t];
      float2 h = base[t * 384 + tid];
      acc.x = fmaf(w, h.x, acc.x);
      acc.y = fmaf(w, h.y, acc.y);
    }
    ushort2 o;
    o.x = f2bf(acc.x); o.y = f2bf(acc.y);
    *(ushort2*)(pooled_bf + (long long)blk * DD + tid * 2) = o;
  }
}

// ---------------------------------------------------------------------------
// K12: per (b, mt): x-rows = pooled @ fc1^T + b (13 tiles, x in LDS+global),
// then qkv-rows = x @ ain^T + b (38 tiles) routed to q/k/vt scratch.
// grid 384 x 256.
// ---------------------------------------------------------------------------
__global__ __launch_bounds__(256) void k_fc1qkv(
    const unsigned short* __restrict__ pooled,
    const unsigned short* __restrict__ fc1_wb, const float* __restrict__ fc1_b,
    const unsigned short* __restrict__ ain_wb, const float* __restrict__ ain_b,
    char* __restrict__ scratch)
{
  const int b = blockIdx.x / 3, mt = blockIdx.x % 3, m0 = mt * 16;
  const int tid = threadIdx.x, wv = tid >> 6, lane = tid & 63;
  const int col = lane & 15, quad = lane >> 4, koff = quad * 8;

  char* sb = scratch + (size_t)b * SB_BLK;
  float* x_f32 = (float*)(sb + SB_XF);
  unsigned short* q_bf  = (unsigned short*)(sb + SB_QB);
  unsigned short* k_bf  = (unsigned short*)(sb + SB_KB);
  unsigned short* vt_bf = (unsigned short*)(sb + SB_VT);

  __shared__ __align__(16) unsigned short xb[16][232];
  // zero pad cols 200..231
  for (int u = tid; u < 16 * 16; u += 256) {
    int row = u >> 4, c = u & 15;
    ((unsigned*)&xb[row][200])[c] = 0u;
  }

  // stage 1: fc1 (K=768)
  const unsigned short* Ab = pooled + (size_t)b * SS * DD;
  for (int t = wv; t < 13; t += 4) {
    int n0 = t * 16;
    f4_t acc = mfma_tile<24>(Ab + (size_t)(m0 + col) * DD + koff,
                             fc1_wb + (size_t)(n0 + col) * DD + koff);
    int gn = n0 + col;
    if (gn < DM) {
      float bv = fc1_b[gn];
#pragma unroll
      for (int r = 0; r < 4; ++r) {
        int row = quad * 4 + r;
        float v = acc[r] + bv;
        x_f32[(m0 + row) * 208 + gn] = v;
        xb[row][gn] = f2bf(v);
      }
    }
  }
  __syncthreads();

  // stage 2: qkv (K=224, A from LDS)
  for (int t = wv; t < 38; t += 4) {
    int n0 = t * 16;
    f4_t acc = mfma_tile_lds<7, 232>(&xb[0][0] + col * 232 + koff,
                                     ain_wb + (size_t)(n0 + col) * 224 + koff);
    int gn = n0 + col;
    if (gn < 600) {
      float bv = ain_b[gn];
#pragma unroll
      for (int r = 0; r < 4; ++r) {
        int gm = m0 + quad * 4 + r;
        unsigned short bfv = f2bf(acc[r] + bv);
        if (gn < 200)      q_bf[gm * 224 + gn] = bfv;
        else if (gn < 400) k_bf[gm * 224 + (gn - 200)] = bfv;
        else if (gm < SS)  vt_bf[(gn - 400) * 64 + gm] = bfv;   // V^T
      }
    }
  }
}

// ---------------------------------------------------------------------------
// K3: fused attention per batch. 128 x 512.
// ---------------------------------------------------------------------------
__global__ __launch_bounds__(512) void k_attn(char* __restrict__ scratch)
{
  const int b = blockIdx.x, tid = threadIdx.x;
  const int wv = tid >> 6, lane = tid & 63;
  const int col = lane & 15, quad = lane >> 4, koff = quad * 8;

  char* sb = scratch + (size_t)b * SB_BLK;
  const unsigned short* q_bf  = (const unsigned short*)(sb + SB_QB);
  const unsigned short* k_bf  = (const unsigned short*)(sb + SB_KB);
  const unsigned short* vt_bf = (const unsigned short*)(sb + SB_VT);
  unsigned short* att_bf = (unsigned short*)(sb + SB_AB);

  __shared__ __align__(16) char smem[16896];
  float*          sc = (float*)smem;                      // [48][52]
  unsigned short* Pb = (unsigned short*)(smem + 9984);    // [48][72]

  for (int t = wv; t < 9; t += 8) {
    int mt = t / 3, nt = t - mt * 3;
    int m0 = mt * 16, n0 = nt * 16;
    f4_t acc = mfma_tile<7>(q_bf + (m0 + col) * 224 + koff,
                            k_bf + (n0 + col) * 224 + koff);
    int gn = n0 + col;
#pragma unroll
    for (int r = 0; r < 4; ++r)
      sc[(m0 + quad * 4 + r) * 52 + gn] = acc[r] * 0.07071067811865475f;
  }
  __syncthreads();

  if (tid < SS) {
    float mx = -1e30f;
    for (int j = 0; j < SS; ++j) mx = fmaxf(mx, sc[tid * 52 + j]);
    float sm = 0.f;
    for (int j = 0; j < SS; ++j) { float e = __expf(sc[tid * 52 + j] - mx); sc[tid * 52 + j] = e; sm += e; }
    float inv = 1.f / sm;
    for (int j = 0; j < SS; ++j) sc[tid * 52 + j] *= inv;
  }
  __syncthreads();
  for (int u = tid; u < 48 * 64; u += 512) {
    int m = u >> 6, k = u & 63;
    Pb[m * 72 + k] = (m < SS && k < SS) ? f2bf(sc[m * 52 + k]) : (unsigned short)0;
  }
  __syncthreads();

  for (int t = wv; t < 3 * 13; t += 8) {
    int mt = t / 13, nt = t - mt * 13;
    int m0 = mt * 16, n0 = nt * 16;
    f4_t acc = mfma_tile_lds<2, 72>(Pb + (m0 + col) * 72 + koff,
                                    vt_bf + (n0 + col) * 64 + koff);
    int gn = n0 + col;
    if (gn < DM) {
#pragma unroll
      for (int r = 0; r < 4; ++r)
        att_bf[(m0 + quad * 4 + r) * 224 + gn] = f2bf(acc[r]);
    }
  }
}

// ---------------------------------------------------------------------------
// K4: per (b, mt): y = x + att@aout^T + b -> LN1 -> f1 = relu(y@lin1^T + b)
//     -> y2 = y + f1@lin2^T + b -> LN2 -> global y2. All mid tensors in LDS.
// grid 384 x 256.
// ---------------------------------------------------------------------------
__global__ __launch_bounds__(256) void k_post(
    const unsigned short* __restrict__ aout_wb, const float* __restrict__ aout_b,
    const float* __restrict__ ln1_g, const float* __restrict__ ln1_b,
    const unsigned short* __restrict__ lin1_wb, const float* __restrict__ lin1_b,
    const unsigned short* __restrict__ lin2_wb, const float* __restrict__ lin2_b,
    const float* __restrict__ ln2_g, const float* __restrict__ ln2_b,
    char* __restrict__ scratch)
{
  const int b = blockIdx.x / 3, mt = blockIdx.x % 3, m0 = mt * 16;
  const int tid = threadIdx.x, wv = tid >> 6, lane = tid & 63;
  const int col = lane & 15, quad = lane >> 4, koff = quad * 8;

  char* sb = scratch + (size_t)b * SB_BLK;
  const unsigned short* att_bf = (const unsigned short*)(sb + SB_AB);
  const float* x_f32 = (const float*)(sb + SB_XF);
  float* y2g = (float*)(sb + SB_Y2);

  __shared__ float tc[16][211];
  __shared__ __align__(16) unsigned short yb[16][232];
  __shared__ __align__(16) unsigned short fb[16][232];
  for (int u = tid; u < 16 * 16; u += 256) {
    int row = u >> 4, c = u & 15;
    ((unsigned*)&yb[row][200])[c] = 0u;
    ((unsigned*)&fb[row][200])[c] = 0u;
  }

  // stage A: aout gemm + bias + residual -> tc
  for (int t = wv; t < 13; t += 4) {
    int n0 = t * 16;
    f4_t acc = mfma_tile<7>(att_bf + (m0 + col) * 224 + koff,
                            aout_wb + (size_t)(n0 + col) * 224 + koff);
    int gn = n0 + col;
    float bv = (gn < DM) ? aout_b[gn] : 0.f;
#pragma unroll
    for (int r = 0; r < 4; ++r) {
      int row = quad * 4 + r;
      float v = acc[r] + bv;
      if (gn < DM) v += x_f32[(m0 + row) * 208 + gn];
      tc[row][gn] = v;
    }
  }
  __syncthreads();

  // stage B: LN1 per row (in place) + bf16 to yb
  for (int r = wv; r < 16; r += 4) {
    float* p = &tc[r][0];
    float vals[4]; float s = 0.f;
#pragma unroll
    for (int i = 0; i < 4; ++i) { int k = lane + 64 * i; vals[i] = (k < DM) ? p[k] : 0.f; s += vals[i]; }
#pragma unroll
    for (int off = 32; off; off >>= 1) s += __shfl_xor(s, off);
    float mean = s * (1.f / DM);
    float vs = 0.f;
#pragma unroll
    for (int i = 0; i < 4; ++i) { int k = lane + 64 * i; if (k < DM) { float d = vals[i] - mean; vs += d * d; } }
#pragma unroll
    for (int off = 32; off; off >>= 1) vs += __shfl_xor(vs, off);
    float rstd = rsqrtf(vs * (1.f / DM) + 1e-5f);
#pragma unroll
    for (int i = 0; i < 4; ++i) {
      int k = lane + 64 * i;
      if (k < DM) {
        float o = (vals[i] - mean) * rstd * ln1_g[k] + ln1_b[k];
        p[k] = o;
        yb[r][k] = f2bf(o);
      }
    }
  }
  __syncthreads();

  // stage C: f1 = relu(y @ lin1^T + b)
  for (int t = wv; t < 13; t += 4) {
    int n0 = t * 16;
    f4_t acc = mfma_tile_lds<7, 232>(&yb[0][0] + col * 232 + koff,
                                     lin1_wb + (size_t)(n0 + col) * 224 + koff);
    int gn = n0 + col;
    if (gn < DM) {
      float bv = lin1_b[gn];
#pragma unroll
      for (int r = 0; r < 4; ++r)
        fb[quad * 4 + r][gn] = f2bf(fmaxf(acc[r] + bv, 0.f));
    }
  }
  __syncthreads();

  // stage D: y2 = y + f1 @ lin2^T + b  (in place into tc)
  for (int t = wv; t < 13; t += 4) {
    int n0 = t * 16;
    f4_t acc = mfma_tile_lds<7, 232>(&fb[0][0] + col * 232 + koff,
                                     lin2_wb + (size_t)(n0 + col) * 224 + koff);
    int gn = n0 + col;
    if (gn < DM) {
      float bv = lin2_b[gn];
#pragma unroll
      for (int r = 0; r < 4; ++r) {
        int row = quad * 4 + r;
        tc[row][gn] = acc[r] + bv + tc[row][gn];
      }
    }
  }
  __syncthreads();

  // stage E: LN2 per row -> global y2
  for (int r = wv; r < 16; r += 4) {
    float* p = &tc[r][0];
    float vals[4]; float s = 0.f;
#pragma unroll
    for (int i = 0; i < 4; ++i) { int k = lane + 64 * i; vals[i] = (k < DM) ? p[k] : 0.f; s += vals[i]; }
#pragma unroll
    for (int off = 32; off; off >>= 1) s += __shfl_xor(s, off);
    float mean = s * (1.f / DM);
    float vs = 0.f;
#pragma unroll
    for (int i = 0; i < 4; ++i) { int k = lane + 64 * i; if (k < DM) { float d = vals[i] - mean; vs += d * d; } }
#pragma unroll
    for (int off = 32; off; off >>= 1) vs += __shfl_xor(vs, off);
    float rstd = rsqrtf(vs * (1.f / DM) + 1e-5f);
    int grow = m0 + r;
#pragma unroll
    for (int i = 0; i < 4; ++i) {
      int k = lane + 64 * i;
      if (k < DM) y2g[grow * 208 + k] = (vals[i] - mean) * rstd * ln2_g[k] + ln2_b[k];
    }
  }
}

// ---------------------------------------------------------------------------
// K5: classifier. One wave per (b, j).
// ---------------------------------------------------------------------------
__global__ __launch_bounds__(256) void k_cls(
    const char* __restrict__ scratch, const float* __restrict__ fcw,
    const float* __restrict__ fcb, float* __restrict__ out)
{
  int gw = blockIdx.x * 4 + (threadIdx.x >> 6);   // b*32 + j
  int lane = threadIdx.x & 63;
  int b = gw >> 5, j = gw & 31;
  const float* y2 = (const float*)(scratch + (size_t)b * SB_BLK + SB_Y2);
  const float* r0 = y2;
  const float* rj = y2 + (1 + j) * 208;
  float a0 = 0.f, a1 = 0.f;
  for (int k = lane; k < DM; k += 64) {
    float u = r0[k], w = rj[k];
    a0 += u * fcw[k]       + w * fcw[200 + k];
    a1 += u * fcw[400 + k] + w * fcw[600 + k];
  }
#pragma unroll
  for (int off = 32; off; off >>= 1) {
    a0 += __shfl_xor(a0, off);
    a1 += __shfl_xor(a1, off);
  }
  if (lane == 0) {
    out[gw * 2 + 0] = a0 + fcb[0];
    out[gw * 2 + 1] = a1 + fcb[1];
  }
}

// ---------------------------------------------------------------------------
extern "C" void kernel_launch(void* const* d_in, const int* in_sizes, int n_in,
                              void* d_out, int out_size, void* d_ws, size_t ws_size,
                              hipStream_t stream)
{
  (void)in_sizes; (void)n_in; (void)out_size; (void)ws_size;
  const float* hidden = (const float*)d_in[0];
  const int*   clause = (const int*)d_in[1];
  const float* fc5_w  = (const float*)d_in[2];
  const float* fc1_w  = (const float*)d_in[4];
  const float* fc1_b  = (const float*)d_in[5];
  const float* ain_w  = (const float*)d_in[6];
  const float* ain_b  = (const float*)d_in[7];
  const float* aout_w = (const float*)d_in[8];
  const float* aout_b = (const float*)d_in[9];
  const float* ln1_g  = (const float*)d_in[10];
  const float* ln1_b  = (const float*)d_in[11];
  const float* lin1_w = (const float*)d_in[12];
  const float* lin1_b = (const float*)d_in[13];
  const float* lin2_w = (const float*)d_in[14];
  const float* lin2_b = (const float*)d_in[15];
  const float* ln2_g  = (const float*)d_in[16];
  const float* ln2_b  = (const float*)d_in[17];
  const float* fc_w   = (const float*)d_in[18];
  const float* fc_b   = (const float*)d_in[19];
  float* out = (float*)d_out;

  char* w8 = (char*)d_ws;
  unsigned short* pooled_bf = (unsigned short*)(w8 + 0);  // [4224][768] + 32KB guard
  char* scratch = w8 + 6520832;                           // 128 * SB_BLK
  size_t wbase = 6520832 + (size_t)NB * SB_BLK;
  unsigned short* fc1_wb  = (unsigned short*)(w8 + wbase);
  unsigned short* ain_wb  = (unsigned short*)(w8 + wbase + 319488);
  unsigned short* aout_wb = (unsigned short*)(w8 + wbase + 591872);
  unsigned short* lin1_wb = (unsigned short*)(w8 + wbase + 685056);
  unsigned short* lin2_wb = (unsigned short*)(w8 + wbase + 778240);

  // 4224 pool blocks + 1203 convert blocks (615,936 threads exactly)
  pc_kernel<<<dim3(NB * SS + 1203), 512, 0, stream>>>(
      hidden, clause, fc5_w, pooled_bf,
      fc1_w, ain_w, aout_w, lin1_w, lin2_w,
      fc1_wb, ain_wb, aout_wb, lin1_wb, lin2_wb, scratch);
  k_fc1qkv<<<dim3(NB * 3), 256, 0, stream>>>(pooled_bf, fc1_wb, fc1_b,
      ain_wb, ain_b, scratch);
  k_attn<<<dim3(NB), 512, 0, stream>>>(scratch);
  k_post<<<dim3(NB * 3), 256, 0, stream>>>(aout_wb, aout_b, ln1_g, ln1_b,
      lin1_wb, lin1_b, lin2_wb, lin2_b, ln2_g, ln2_b, scratch);
  k_cls<<<dim3(1024), 256, 0, stream>>>(scratch, fc_w, fc_b, out);
}

// Round 6
// 382.129 us; speedup vs baseline: 1.2060x; 1.0390x over previous
//
#include <hip/hip_runtime.h>

#define NB 128
#define LL 512
#define DD 768
#define JJ 32
#define SS 33
#define DM 200

typedef __attribute__((ext_vector_type(8))) short bf8_t;   // 8 bf16 (4 VGPRs)
typedef __attribute__((ext_vector_type(4))) float f4_t;    // MFMA C/D

// per-batch scratch block (bytes)
#define SB_XF   0                 // x_f32 [48][208] f32
#define SB_QB   61440             // q_bf  [48][224]
#define SB_KB   82944             // k_bf  [48][224]
#define SB_VT   104448            // vt_bf [208][64]
#define SB_Y2   235520            // y2_f32[48][208] f32
#define SB_BLK  275456

static __device__ __forceinline__ unsigned short f2bf(float f) {
  unsigned u = __float_as_uint(f);
  return (unsigned short)((u + 0x7FFFu + ((u >> 16) & 1u)) >> 16);  // RNE
}

template<int KS>
static __device__ __forceinline__ f4_t mfma_tile(
    const unsigned short* pa, const unsigned short* pw)
{
  f4_t acc = {0.f, 0.f, 0.f, 0.f};
  bf8_t a = *(const bf8_t*)pa;
  bf8_t w = *(const bf8_t*)pw;
#pragma unroll
  for (int s = 1; s < KS; ++s) {
    bf8_t a2 = *(const bf8_t*)(pa + 32 * s);
    bf8_t w2 = *(const bf8_t*)(pw + 32 * s);
    acc = __builtin_amdgcn_mfma_f32_16x16x32_bf16(a, w, acc, 0, 0, 0);
    a = a2; w = w2;
  }
  acc = __builtin_amdgcn_mfma_f32_16x16x32_bf16(a, w, acc, 0, 0, 0);
  return acc;
}

template<int KS>
static __device__ __forceinline__ f4_t mfma_tile_lds(
    const unsigned short* pa, const unsigned short* pw)
{
  f4_t acc = {0.f, 0.f, 0.f, 0.f};
#pragma unroll
  for (int s = 0; s < KS; ++s) {
    bf8_t a = *(const bf8_t*)(pa + 32 * s);
    bf8_t w = *(const bf8_t*)(pw + 32 * s);
    acc = __builtin_amdgcn_mfma_f32_16x16x32_bf16(a, w, acc, 0, 0, 0);
  }
  return acc;
}

// ---------------------------------------------------------------------------
// PC kernel: blocks [0, 4224) = fused pool; blocks [4224, ...) = weight
// convert + scratch pad-zero.
// ---------------------------------------------------------------------------
__global__ __launch_bounds__(512) void pc_kernel(
    const float* __restrict__ hidden, const int* __restrict__ clause,
    const float* __restrict__ fc5w, unsigned short* __restrict__ pooled_bf,
    const float* __restrict__ fc1_w, const float* __restrict__ ain_w,
    const float* __restrict__ aout_w, const float* __restrict__ lin1_w,
    const float* __restrict__ lin2_w,
    unsigned short* __restrict__ fc1_wb, unsigned short* __restrict__ ain_wb,
    unsigned short* __restrict__ aout_wb, unsigned short* __restrict__ lin1_wb,
    unsigned short* __restrict__ lin2_wb, char* __restrict__ scratch)
{
  const int tid = threadIdx.x;
  if (blockIdx.x >= NB * SS) {
    int t = (blockIdx.x - NB * SS) * 512 + tid;
    if (t < 208 * 768) {
      int n = t / 768, k = t - n * 768;
      fc1_wb[t] = f2bf((n < 200) ? fc1_w[n * 768 + k] : 0.f);
      return;
    }
    t -= 208 * 768;
    if (t < 608 * 224) {
      int n = t / 224, k = t - n * 224;
      ain_wb[t] = f2bf((n < 600 && k < 200) ? ain_w[n * 200 + k] : 0.f);
      return;
    }
    t -= 608 * 224;
    if (t < 208 * 224) {
      int n = t / 224, k = t - n * 224;
      aout_wb[t] = f2bf((n < 200 && k < 200) ? aout_w[n * 200 + k] : 0.f);
      return;
    }
    t -= 208 * 224;
    if (t < 208 * 224) {
      int n = t / 224, k = t - n * 224;
      lin1_wb[t] = f2bf((n < 200 && k < 200) ? lin1_w[n * 200 + k] : 0.f);
      return;
    }
    t -= 208 * 224;
    if (t < 208 * 224) {
      int n = t / 224, k = t - n * 224;
      lin2_wb[t] = f2bf((n < 200 && k < 200) ? lin2_w[n * 200 + k] : 0.f);
      return;
    }
    t -= 208 * 224;
    if (t < NB * 1344) {          // pad-zero: QB/KB cols 192-223, VT cols 32-63
      int b = t / 1344, r = t - b * 1344;
      char* sb = scratch + (size_t)b * SB_BLK;
      const uint4 z = make_uint4(0, 0, 0, 0);
      if (r < 384) {
        int bi = r / 192, rr = r - bi * 192;
        int row = rr >> 2, c = rr & 3;
        int off = (bi == 0) ? SB_QB : SB_KB;
        *(uint4*)((unsigned short*)(sb + off) + row * 224 + 192 + c * 8) = z;
      } else {
        int rr = r - 384;
        int row = rr >> 2, c = rr & 3;
        *(uint4*)((unsigned short*)(sb + SB_VT) + row * 64 + 32 + c * 8) = z;
      }
    }
    return;
  }

  // -------- pool part: block = (b, s) --------
  int blk = blockIdx.x;
  int b = blk / SS;
  int s = blk - b * SS;
  int t0 = (s == 0) ? 0 : clause[b * JJ + s - 1];
  int t1 = (s == JJ) ? LL : clause[b * JJ + s];
  int nt = t1 - t0;
  if (nt > 64) nt = 64;
  if (nt < 1) nt = 1;

  __shared__ float wsm[64];
  int wave = tid >> 6, lane = tid & 63;

  const float4* w4 = (const float4*)fc5w;
  for (int t = t0 + wave; t < t0 + nt; t += 8) {
    const float4* hp = (const float4*)(hidden + ((long long)b * LL + t) * DD);
    float acc = 0.f;
#pragma unroll
    for (int i = 0; i < 3; ++i) {
      float4 h = hp[lane + 64 * i];
      float4 w = w4[lane + 64 * i];
      acc += h.x * w.x + h.y * w.y + h.z * w.z + h.w * w.w;
    }
#pragma unroll
    for (int off = 32; off; off >>= 1) acc += __shfl_xor(acc, off);
    if (lane == 0) wsm[t - t0] = acc;
  }
  __syncthreads();

  if (wave == 0) {
    float v = (lane < nt) ? wsm[lane] : -__builtin_inff();
    float mx = v;
#pragma unroll
    for (int off = 32; off; off >>= 1) mx = fmaxf(mx, __shfl_xor(mx, off));
    float e = (lane < nt) ? __expf(v - mx) : 0.f;
    float sm = e;
#pragma unroll
    for (int off = 32; off; off >>= 1) sm += __shfl_xor(sm, off);
    if (lane < nt) wsm[lane] = e / sm;
  }
  __syncthreads();

  if (tid < 384) {
    const float2* base = (const float2*)(hidden + ((long long)b * LL + t0) * DD);
    float2 acc = make_float2(0.f, 0.f);
#pragma unroll 4
    for (int t = 0; t < nt; ++t) {
      float w = wsm[t];
      float2 h = base[t * 384 + tid];
      acc.x = fmaf(w, h.x, acc.x);
      acc.y = fmaf(w, h.y, acc.y);
    }
    ushort2 o;
    o.x = f2bf(acc.x); o.y = f2bf(acc.y);
    *(ushort2*)(pooled_bf + (long long)blk * DD + tid * 2) = o;
  }
}

// ---------------------------------------------------------------------------
// K1: per (b, mt), 512 thr: x = pooled@fc1^T + b (13 tiles, x -> LDS+global),
// qkv = x@ain^T + b (38 tiles) routed to q/k/vt scratch.
// ---------------------------------------------------------------------------
__global__ __launch_bounds__(512) void k_fc1qkv(
    const unsigned short* __restrict__ pooled,
    const unsigned short* __restrict__ fc1_wb, const float* __restrict__ fc1_b,
    const unsigned short* __restrict__ ain_wb, const float* __restrict__ ain_b,
    char* __restrict__ scratch)
{
  const int b = blockIdx.x / 3, mt = blockIdx.x % 3, m0 = mt * 16;
  const int tid = threadIdx.x, wv = tid >> 6, lane = tid & 63;
  const int col = lane & 15, quad = lane >> 4, koff = quad * 8;

  char* sb = scratch + (size_t)b * SB_BLK;
  float* x_f32 = (float*)(sb + SB_XF);
  unsigned short* q_bf  = (unsigned short*)(sb + SB_QB);
  unsigned short* k_bf  = (unsigned short*)(sb + SB_KB);
  unsigned short* vt_bf = (unsigned short*)(sb + SB_VT);

  __shared__ __align__(16) unsigned short xb[16][232];
  for (int u = tid; u < 16 * 16; u += 512) {
    int row = u >> 4, c = u & 15;
    ((unsigned*)&xb[row][200])[c] = 0u;
  }

  const unsigned short* Ab = pooled + (size_t)b * SS * DD;
  for (int t = wv; t < 13; t += 8) {
    int n0 = t * 16;
    f4_t acc = mfma_tile<24>(Ab + (size_t)(m0 + col) * DD + koff,
                             fc1_wb + (size_t)(n0 + col) * DD + koff);
    int gn = n0 + col;
    if (gn < DM) {
      float bv = fc1_b[gn];
#pragma unroll
      for (int r = 0; r < 4; ++r) {
        int row = quad * 4 + r;
        float v = acc[r] + bv;
        x_f32[(m0 + row) * 208 + gn] = v;
        xb[row][gn] = f2bf(v);
      }
    }
  }
  __syncthreads();

  for (int t = wv; t < 38; t += 8) {
    int n0 = t * 16;
    f4_t acc = mfma_tile_lds<7>(&xb[0][0] + col * 232 + koff,
                                ain_wb + (size_t)(n0 + col) * 224 + koff);
    int gn = n0 + col;
    if (gn < 600) {
      float bv = ain_b[gn];
#pragma unroll
      for (int r = 0; r < 4; ++r) {
        int gm = m0 + quad * 4 + r;
        unsigned short bfv = f2bf(acc[r] + bv);
        if (gn < 200)      q_bf[gm * 224 + gn] = bfv;
        else if (gn < 400) k_bf[gm * 224 + (gn - 200)] = bfv;
        else if (gm < SS)  vt_bf[(gn - 400) * 64 + gm] = bfv;   // V^T
      }
    }
  }
}

// ---------------------------------------------------------------------------
// K2: per (b, mt), 512 thr: 16 own Q-rows through attention + aout + LN1 +
// FFN + LN2, all intermediates in LDS. y2 -> global scratch.
// ---------------------------------------------------------------------------
__global__ __launch_bounds__(512) void k_postattn(
    const unsigned short* __restrict__ aout_wb, const float* __restrict__ aout_b,
    const float* __restrict__ ln1_g, const float* __restrict__ ln1_b,
    const unsigned short* __restrict__ lin1_wb, const float* __restrict__ lin1_b,
    const unsigned short* __restrict__ lin2_wb, const float* __restrict__ lin2_b,
    const float* __restrict__ ln2_g, const float* __restrict__ ln2_b,
    char* __restrict__ scratch)
{
  const int b = blockIdx.x / 3, mt = blockIdx.x % 3, m0 = mt * 16;
  const int tid = threadIdx.x, wv = tid >> 6, lane = tid & 63;
  const int col = lane & 15, quad = lane >> 4, koff = quad * 8;

  char* sb = scratch + (size_t)b * SB_BLK;
  const unsigned short* q_bf  = (const unsigned short*)(sb + SB_QB);
  const unsigned short* k_bf  = (const unsigned short*)(sb + SB_KB);
  const unsigned short* vt_bf = (const unsigned short*)(sb + SB_VT);
  const float* x_f32 = (const float*)(sb + SB_XF);
  float* y2g = (float*)(sb + SB_Y2);

  __shared__ float tc[16][211];                         // scores then C-tile
  __shared__ __align__(16) unsigned short Pb[16][72];   // softmax(P) bf16
  __shared__ __align__(16) unsigned short yb[16][232];  // LN1 out bf16
  __shared__ __align__(16) unsigned short fb[16][232];  // att, then f1
  for (int u = tid; u < 16 * 16; u += 512) {
    int row = u >> 4, c = u & 15;
    ((unsigned*)&yb[row][200])[c] = 0u;
    ((unsigned*)&fb[row][200])[c] = 0u;
  }

  // ---- S: scores rows m0..m0+15 vs all 48 K rows (3 tiles, K=224) ----
  for (int t = wv; t < 3; t += 8) {
    int n0 = t * 16;
    f4_t acc = mfma_tile<7>(q_bf + (m0 + col) * 224 + koff,
                            k_bf + (n0 + col) * 224 + koff);
    int gn = n0 + col;
#pragma unroll
    for (int r = 0; r < 4; ++r)
      tc[quad * 4 + r][gn] = acc[r] * 0.07071067811865475f;
  }
  __syncthreads();

  // ---- softmax rows (2 rows per wave), write P bf16 (pad-zeroed) ----
  for (int r = wv; r < 16; r += 8) {
    bool live = (m0 + r) < SS;
    float v = (lane < SS && live) ? tc[r][lane] : -__builtin_inff();
    float mx = v;
#pragma unroll
    for (int off = 32; off; off >>= 1) mx = fmaxf(mx, __shfl_xor(mx, off));
    float e = (lane < SS && live) ? __expf(v - mx) : 0.f;
    float sm = e;
#pragma unroll
    for (int off = 32; off; off >>= 1) sm += __shfl_xor(sm, off);
    Pb[r][lane] = (lane < SS && live) ? f2bf(e / sm) : (unsigned short)0;
  }
  __syncthreads();

  // ---- PV: att = P @ V  (13 tiles, K=64) -> fb bf16 ----
  for (int t = wv; t < 13; t += 8) {
    int n0 = t * 16;
    f4_t acc = mfma_tile_lds<2>(&Pb[0][0] + col * 72 + koff,
                                vt_bf + (n0 + col) * 64 + koff);
    int gn = n0 + col;
    if (gn < DM) {
#pragma unroll
      for (int r = 0; r < 4; ++r)
        fb[quad * 4 + r][gn] = f2bf(acc[r]);
    }
  }
  __syncthreads();

  // ---- A: y = x + att @ aout^T + b -> tc ----
  for (int t = wv; t < 13; t += 8) {
    int n0 = t * 16;
    f4_t acc = mfma_tile_lds<7>(&fb[0][0] + col * 232 + koff,
                                aout_wb + (size_t)(n0 + col) * 224 + koff);
    int gn = n0 + col;
    float bv = (gn < DM) ? aout_b[gn] : 0.f;
#pragma unroll
    for (int r = 0; r < 4; ++r) {
      int row = quad * 4 + r;
      float v = acc[r] + bv;
      if (gn < DM) v += x_f32[(m0 + row) * 208 + gn];
      tc[row][gn] = v;
    }
  }
  __syncthreads();

  // ---- LN1 -> tc (in place) + yb bf16 ----
  for (int r = wv; r < 16; r += 8) {
    float* p = &tc[r][0];
    float vals[4]; float s = 0.f;
#pragma unroll
    for (int i = 0; i < 4; ++i) { int k = lane + 64 * i; vals[i] = (k < DM) ? p[k] : 0.f; s += vals[i]; }
#pragma unroll
    for (int off = 32; off; off >>= 1) s += __shfl_xor(s, off);
    float mean = s * (1.f / DM);
    float vs = 0.f;
#pragma unroll
    for (int i = 0; i < 4; ++i) { int k = lane + 64 * i; if (k < DM) { float d = vals[i] - mean; vs += d * d; } }
#pragma unroll
    for (int off = 32; off; off >>= 1) vs += __shfl_xor(vs, off);
    float rstd = rsqrtf(vs * (1.f / DM) + 1e-5f);
#pragma unroll
    for (int i = 0; i < 4; ++i) {
      int k = lane + 64 * i;
      if (k < DM) {
        float o = (vals[i] - mean) * rstd * ln1_g[k] + ln1_b[k];
        p[k] = o;
        yb[r][k] = f2bf(o);
      }
    }
  }
  __syncthreads();

  // ---- C: f1 = relu(y @ lin1^T + b) -> fb (att dead) ----
  for (int t = wv; t < 13; t += 8) {
    int n0 = t * 16;
    f4_t acc = mfma_tile_lds<7>(&yb[0][0] + col * 232 + koff,
                                lin1_wb + (size_t)(n0 + col) * 224 + koff);
    int gn = n0 + col;
    if (gn < DM) {
      float bv = lin1_b[gn];
#pragma unroll
      for (int r = 0; r < 4; ++r)
        fb[quad * 4 + r][gn] = f2bf(fmaxf(acc[r] + bv, 0.f));
    }
  }
  __syncthreads();

  // ---- D: y2 = y + f1 @ lin2^T + b -> tc ----
  for (int t = wv; t < 13; t += 8) {
    int n0 = t * 16;
    f4_t acc = mfma_tile_lds<7>(&fb[0][0] + col * 232 + koff,
                                lin2_wb + (size_t)(n0 + col) * 224 + koff);
    int gn = n0 + col;
    if (gn < DM) {
      float bv = lin2_b[gn];
#pragma unroll
      for (int r = 0; r < 4; ++r) {
        int row = quad * 4 + r;
        tc[row][gn] = acc[r] + bv + tc[row][gn];
      }
    }
  }
  __syncthreads();

  // ---- LN2 -> global y2 ----
  for (int r = wv; r < 16; r += 8) {
    float* p = &tc[r][0];
    float vals[4]; float s = 0.f;
#pragma unroll
    for (int i = 0; i < 4; ++i) { int k = lane + 64 * i; vals[i] = (k < DM) ? p[k] : 0.f; s += vals[i]; }
#pragma unroll
    for (int off = 32; off; off >>= 1) s += __shfl_xor(s, off);
    float mean = s * (1.f / DM);
    float vs = 0.f;
#pragma unroll
    for (int i = 0; i < 4; ++i) { int k = lane + 64 * i; if (k < DM) { float d = vals[i] - mean; vs += d * d; } }
#pragma unroll
    for (int off = 32; off; off >>= 1) vs += __shfl_xor(vs, off);
    float rstd = rsqrtf(vs * (1.f / DM) + 1e-5f);
    int grow = m0 + r;
#pragma unroll
    for (int i = 0; i < 4; ++i) {
      int k = lane + 64 * i;
      if (k < DM) y2g[grow * 208 + k] = (vals[i] - mean) * rstd * ln2_g[k] + ln2_b[k];
    }
  }
}

// ---------------------------------------------------------------------------
// K3: classifier. One wave per (b, j).
// ---------------------------------------------------------------------------
__global__ __launch_bounds__(256) void k_cls(
    const char* __restrict__ scratch, const float* __restrict__ fcw,
    const float* __restrict__ fcb, float* __restrict__ out)
{
  int gw = blockIdx.x * 4 + (threadIdx.x >> 6);   // b*32 + j
  int lane = threadIdx.x & 63;
  int b = gw >> 5, j = gw & 31;
  const float* y2 = (const float*)(scratch + (size_t)b * SB_BLK + SB_Y2);
  const float* r0 = y2;
  const float* rj = y2 + (1 + j) * 208;
  float a0 = 0.f, a1 = 0.f;
  for (int k = lane; k < DM; k += 64) {
    float u = r0[k], w = rj[k];
    a0 += u * fcw[k]       + w * fcw[200 + k];
    a1 += u * fcw[400 + k] + w * fcw[600 + k];
  }
#pragma unroll
  for (int off = 32; off; off >>= 1) {
    a0 += __shfl_xor(a0, off);
    a1 += __shfl_xor(a1, off);
  }
  if (lane == 0) {
    out[gw * 2 + 0] = a0 + fcb[0];
    out[gw * 2 + 1] = a1 + fcb[1];
  }
}

// ---------------------------------------------------------------------------
extern "C" void kernel_launch(void* const* d_in, const int* in_sizes, int n_in,
                              void* d_out, int out_size, void* d_ws, size_t ws_size,
                              hipStream_t stream)
{
  (void)in_sizes; (void)n_in; (void)out_size; (void)ws_size;
  const float* hidden = (const float*)d_in[0];
  const int*   clause = (const int*)d_in[1];
  const float* fc5_w  = (const float*)d_in[2];
  const float* fc1_w  = (const float*)d_in[4];
  const float* fc1_b  = (const float*)d_in[5];
  const float* ain_w  = (const float*)d_in[6];
  const float* ain_b  = (const float*)d_in[7];
  const float* aout_w = (const float*)d_in[8];
  const float* aout_b = (const float*)d_in[9];
  const float* ln1_g  = (const float*)d_in[10];
  const float* ln1_b  = (const float*)d_in[11];
  const float* lin1_w = (const float*)d_in[12];
  const float* lin1_b = (const float*)d_in[13];
  const float* lin2_w = (const float*)d_in[14];
  const float* lin2_b = (const float*)d_in[15];
  const float* ln2_g  = (const float*)d_in[16];
  const float* ln2_b  = (const float*)d_in[17];
  const float* fc_w   = (const float*)d_in[18];
  const float* fc_b   = (const float*)d_in[19];
  float* out = (float*)d_out;

  char* w8 = (char*)d_ws;
  unsigned short* pooled_bf = (unsigned short*)(w8 + 0);  // [4224][768] + 32KB guard
  char* scratch = w8 + 6520832;                           // 128 * SB_BLK
  size_t wbase = 6520832 + (size_t)NB * SB_BLK;
  unsigned short* fc1_wb  = (unsigned short*)(w8 + wbase);
  unsigned short* ain_wb  = (unsigned short*)(w8 + wbase + 319488);
  unsigned short* aout_wb = (unsigned short*)(w8 + wbase + 591872);
  unsigned short* lin1_wb = (unsigned short*)(w8 + wbase + 685056);
  unsigned short* lin2_wb = (unsigned short*)(w8 + wbase + 778240);

  // 4224 pool blocks + 1187 convert/pad blocks
  pc_kernel<<<dim3(NB * SS + 1187), 512, 0, stream>>>(
      hidden, clause, fc5_w, pooled_bf,
      fc1_w, ain_w, aout_w, lin1_w, lin2_w,
      fc1_wb, ain_wb, aout_wb, lin1_wb, lin2_wb, scratch);
  k_fc1qkv<<<dim3(NB * 3), 512, 0, stream>>>(pooled_bf, fc1_wb, fc1_b,
      ain_wb, ain_b, scratch);
  k_postattn<<<dim3(NB * 3), 512, 0, stream>>>(aout_wb, aout_b, ln1_g, ln1_b,
      lin1_wb, lin1_b, lin2_wb, lin2_b, ln2_g, ln2_b, scratch);
  k_cls<<<dim3(1024), 256, 0, stream>>>(scratch, fc_w, fc_b, out);
}